// Round 2
// baseline (4403.080 us; speedup 1.0000x reference)
//
#include <hip/hip_runtime.h>

#define EMB_DIM 64
#define BSHIFT 7
#define BROWS 128              // rows per bucket
#define NB_MAX 2048            // hist/scan kernels (global-sized)
#define NB_SCAT 1216           // scatter LDS arrays; nb = 1172 for this problem
#define EPB 8192               // edges per partition block
#define PT 512                 // scatter-kernel threads
#define HT 256                 // hist-kernel threads

// bucket-stage pack: col (18b) | row_local (7b) << 18 ; val in high 32
static __device__ __forceinline__ unsigned long long pack_b(int rl, int c, float v) {
    unsigned int lo = (unsigned int)c | ((unsigned int)rl << 18);
    return (unsigned long long)lo | ((unsigned long long)__float_as_uint(v) << 32);
}

static __device__ __forceinline__ unsigned short f2bf(float f) {   // RNE
    unsigned int u = __float_as_uint(f);
    return (unsigned short)((u + 0x7FFFu + ((u >> 16) & 1u)) >> 16);
}
static __device__ __forceinline__ float bf2f(unsigned short b) {
    return __uint_as_float((unsigned int)b << 16);
}

// ---------- init: acc(fp32) = concat(user,item); x(bf16) = same; zero btotal ----------
__global__ void lgcn_init(const float* __restrict__ user_w,
                          const float* __restrict__ item_w,
                          float* __restrict__ acc,
                          unsigned short* __restrict__ x,
                          int* __restrict__ btotal, int nb,
                          int user_n4, int n4) {
    int i = blockIdx.x * blockDim.x + threadIdx.x;
    if (i < nb) btotal[i] = 0;
    if (i >= n4) return;
    float4 v;
    if (i < user_n4) v = ((const float4*)user_w)[i];
    else             v = ((const float4*)item_w)[i - user_n4];
    ((float4*)acc)[i] = v;
    ushort4 b;
    b.x = f2bf(v.x); b.y = f2bf(v.y); b.z = f2bf(v.z); b.w = f2bf(v.w);
    ((ushort4*)x)[i] = b;
}

// ---------- pass 1: per-block LDS hist -> global bucket totals ----------
__global__ void k_hist(const int* __restrict__ erow, int* __restrict__ btotal,
                       int nb, long long nnz) {
    __shared__ int h[NB_MAX];
    int t = threadIdx.x;
    for (int b = t; b < nb; b += HT) h[b] = 0;
    __syncthreads();
    long long base = (long long)blockIdx.x * EPB;
    const int4* erow4 = (const int4*)erow;
    #pragma unroll
    for (int k = 0; k < EPB / HT / 4; ++k) {
        long long e = base + (long long)(k * HT + t) * 4;
        if (e + 4 <= nnz) {
            int4 r = erow4[e >> 2];
            atomicAdd(&h[r.x >> BSHIFT], 1);
            atomicAdd(&h[r.y >> BSHIFT], 1);
            atomicAdd(&h[r.z >> BSHIFT], 1);
            atomicAdd(&h[r.w >> BSHIFT], 1);
        } else if (e < nnz) {
            for (long long q = e; q < nnz; ++q) atomicAdd(&h[erow[q] >> BSHIFT], 1);
        }
    }
    __syncthreads();
    for (int b = t; b < nb; b += HT) {
        int c = h[b];
        if (c) atomicAdd(&btotal[b], c);
    }
}

// ---------- pass 2: exclusive scan over bucket totals -> bbase, gcur ----------
__global__ void k_scan_buckets(const int* __restrict__ btotal, int* __restrict__ bbase,
                               int* __restrict__ gcur, int nb) {
    __shared__ int s[256];
    int t = threadIdx.x;
    int v[8]; int tot = 0;
    #pragma unroll
    for (int k = 0; k < 8; ++k) {
        int idx = t * 8 + k;
        v[k] = (idx < nb) ? btotal[idx] : 0;
        tot += v[k];
    }
    s[t] = tot; __syncthreads();
    for (int d = 1; d < 256; d <<= 1) {
        int add = (t >= d) ? s[t - d] : 0;
        __syncthreads(); s[t] += add; __syncthreads();
    }
    int off = s[t] - tot;
    #pragma unroll
    for (int k = 0; k < 8; ++k) {
        int idx = t * 8 + k;
        if (idx < nb) { bbase[idx] = off; gcur[idx] = off; }
        off += v[k];
    }
}

// ---------- pass 3: LDS-staged bucket-sorted scatter, coalesced write-out ----------
__global__ __launch_bounds__(PT) void k_scatter_staged(
        const int* __restrict__ erow, const int* __restrict__ ecol,
        const float* __restrict__ eval_, int* __restrict__ gcur,
        unsigned long long* __restrict__ ebuf, int nb, long long nnz) {
    __shared__ unsigned long long staged[EPB];   // 64 KB
    __shared__ unsigned short sbid[EPB];         // 16 KB
    __shared__ int lhist[NB_SCAT];               // 4.75 KB (count -> delta)
    __shared__ int lscan[NB_SCAT];               // 4.75 KB
    __shared__ int lcur[NB_SCAT];                // 4.75 KB
    __shared__ int tsum[PT];                     // 2 KB

    int t = threadIdx.x;
    for (int b = t; b < nb; b += PT) lhist[b] = 0;
    __syncthreads();

    long long base = (long long)blockIdx.x * EPB;
    int m = (int)((nnz - base < (long long)EPB) ? (nnz - base) : (long long)EPB);

    // local histogram of this block's edges
    #pragma unroll
    for (int k = 0; k < EPB / PT / 4; ++k) {
        long long e = base + (long long)(k * PT + t) * 4;
        if (e + 4 <= nnz) {
            int4 r = ((const int4*)erow)[e >> 2];
            atomicAdd(&lhist[r.x >> BSHIFT], 1);
            atomicAdd(&lhist[r.y >> BSHIFT], 1);
            atomicAdd(&lhist[r.z >> BSHIFT], 1);
            atomicAdd(&lhist[r.w >> BSHIFT], 1);
        } else if (e < nnz) {
            for (long long q = e; q < nnz; ++q) atomicAdd(&lhist[erow[q] >> BSHIFT], 1);
        }
    }
    __syncthreads();

    // block exclusive scan over nb buckets
    int per = (nb + PT - 1) / PT;
    int first = t * per;
    int s = 0;
    for (int k = 0; k < per; ++k) {
        int b = first + k;
        if (b < nb) s += lhist[b];
    }
    tsum[t] = s;
    __syncthreads();
    for (int d = 1; d < PT; d <<= 1) {
        int add = (t >= d) ? tsum[t - d] : 0;
        __syncthreads(); tsum[t] += add; __syncthreads();
    }
    int off = tsum[t] - s;
    for (int k = 0; k < per; ++k) {
        int b = first + k;
        if (b < nb) { lscan[b] = off; lcur[b] = off; off += lhist[b]; }
    }
    __syncthreads();

    // reserve contiguous global chunks; lhist becomes delta = gbase - lstart
    for (int b = t; b < nb; b += PT) {
        int c = lhist[b];
        int g = c ? atomicAdd(&gcur[b], c) : 0;
        lhist[b] = g - lscan[b];
    }
    __syncthreads();

    // stage-in: bucket-sorted within LDS
    #pragma unroll
    for (int k = 0; k < EPB / PT / 4; ++k) {
        long long e = base + (long long)(k * PT + t) * 4;
        if (e + 4 <= nnz) {
            int4   r = ((const int4*)erow)[e >> 2];
            int4   c = ((const int4*)ecol)[e >> 2];
            float4 v = ((const float4*)eval_)[e >> 2];
            int b0 = r.x >> BSHIFT, b1 = r.y >> BSHIFT, b2 = r.z >> BSHIFT, b3 = r.w >> BSHIFT;
            int p0 = atomicAdd(&lcur[b0], 1);
            int p1 = atomicAdd(&lcur[b1], 1);
            int p2 = atomicAdd(&lcur[b2], 1);
            int p3 = atomicAdd(&lcur[b3], 1);
            staged[p0] = pack_b(r.x & (BROWS - 1), c.x, v.x); sbid[p0] = (unsigned short)b0;
            staged[p1] = pack_b(r.y & (BROWS - 1), c.y, v.y); sbid[p1] = (unsigned short)b1;
            staged[p2] = pack_b(r.z & (BROWS - 1), c.z, v.z); sbid[p2] = (unsigned short)b2;
            staged[p3] = pack_b(r.w & (BROWS - 1), c.w, v.w); sbid[p3] = (unsigned short)b3;
        } else if (e < nnz) {
            for (long long q = e; q < nnz; ++q) {
                int r = erow[q]; int b = r >> BSHIFT;
                int p = atomicAdd(&lcur[b], 1);
                staged[p] = pack_b(r & (BROWS - 1), ecol[q], eval_[q]);
                sbid[p] = (unsigned short)b;
            }
        }
    }
    __syncthreads();

    // write-out: consecutive staged entries -> contiguous destination runs
    for (int i = t; i < m; i += PT) {
        unsigned long long v = staged[i];
        int b = sbid[i];
        __builtin_nontemporal_store(v, &ebuf[lhist[b] + i]);
    }
}

// ---------- bucketed SpMM: LDS fp32 accumulation, order-free ----------
__global__ __launch_bounds__(256) void lgcn_spmm_bucket(
        const int* __restrict__ bbase, const int* __restrict__ btotal,
        const unsigned long long* __restrict__ ebuf,
        const unsigned short* __restrict__ x,
        unsigned short* __restrict__ y,
        float* __restrict__ acc,
        float scale, int is_last, int n) {
    __shared__ float lacc[BROWS * EMB_DIM];   // 32 KB
    int t = threadIdx.x;
    {
        float4 z = make_float4(0.f, 0.f, 0.f, 0.f);
        for (int i = t * 4; i < BROWS * EMB_DIM; i += 256 * 4)
            *(float4*)&lacc[i] = z;
    }
    __syncthreads();

    int bkt   = blockIdx.x;
    int start = bbase[bkt];
    int m     = btotal[bkt];
    int w = t >> 6, lane = t & 63;

    int j = w * 8;
    for (; j + 8 <= m; j += 32) {
        unsigned long long e[8];
        #pragma unroll
        for (int k = 0; k < 8; ++k) e[k] = ebuf[start + j + k];
        float pv[8]; int rl[8];
        #pragma unroll
        for (int k = 0; k < 8; ++k) {
            unsigned int lo = (unsigned int)e[k];
            float v = __uint_as_float((unsigned int)(e[k] >> 32));
            float u = bf2f(x[(size_t)(lo & 0x3FFFFu) * EMB_DIM + lane]);
            pv[k] = v * u;
            rl[k] = (int)((lo >> 18) & (BROWS - 1));
        }
        #pragma unroll
        for (int k = 0; k < 8; ++k)
            atomicAdd(&lacc[rl[k] * EMB_DIM + lane], pv[k]);
    }
    // tail for this wave (at most one partial 8-chunk lands in one wave's range)
    for (int q = j; q < m && q < j + 8; ++q) {
        unsigned long long e = ebuf[start + q];
        unsigned int lo = (unsigned int)e;
        float v = __uint_as_float((unsigned int)(e >> 32));
        float u = bf2f(x[(size_t)(lo & 0x3FFFFu) * EMB_DIM + lane]);
        atomicAdd(&lacc[(int)((lo >> 18) & (BROWS - 1)) * EMB_DIM + lane], v * u);
    }
    __syncthreads();

    // epilogue: y = bf16(sum); acc += sum (scale on last layer)
    int r0  = bkt << BSHIFT;
    int rows = (n - r0 < BROWS) ? (n - r0) : BROWS;
    int cnt  = rows * EMB_DIM;
    size_t gbase = (size_t)r0 * EMB_DIM;
    for (int i = t * 4; i < cnt; i += 256 * 4) {
        float4 sv = *(float4*)&lacc[i];
        ushort4 b;
        b.x = f2bf(sv.x); b.y = f2bf(sv.y); b.z = f2bf(sv.z); b.w = f2bf(sv.w);
        *(ushort4*)&y[gbase + i] = b;
        float4 a = *(float4*)&acc[gbase + i];
        a.x += sv.x; a.y += sv.y; a.z += sv.z; a.w += sv.w;
        if (is_last) { a.x *= scale; a.y *= scale; a.z *= scale; a.w *= scale; }
        *(float4*)&acc[gbase + i] = a;
    }
}

extern "C" void kernel_launch(void* const* d_in, const int* in_sizes, int n_in,
                              void* d_out, int out_size, void* d_ws, size_t ws_size,
                              hipStream_t stream) {
    const float* user_w = (const float*)d_in[0];
    const float* item_w = (const float*)d_in[1];
    const int*   erow   = (const int*)d_in[2];
    const int*   ecol   = (const int*)d_in[3];
    const float* eval_  = (const float*)d_in[4];

    int n_users = in_sizes[0] / EMB_DIM;
    int n_items = in_sizes[1] / EMB_DIM;
    int n_total = n_users + n_items;
    long long nnz = in_sizes[2];

    int nb     = (n_total + BROWS - 1) >> BSHIFT;
    int nparts = (int)((nnz + EPB - 1) / EPB);

    // workspace layout
    char* ws = (char*)d_ws;
    unsigned short* x = (unsigned short*)ws;    ws += (size_t)n_total * EMB_DIM * 2;
    unsigned short* y = (unsigned short*)ws;    ws += (size_t)n_total * EMB_DIM * 2;
    unsigned long long* ebuf = (unsigned long long*)ws; ws += (size_t)nnz * 8;
    int* btotal = (int*)ws;                     ws += (size_t)nb * 4;
    int* bbase  = (int*)ws;                     ws += (size_t)nb * 4;
    int* gcur   = (int*)ws;                     ws += (size_t)nb * 4;

    float* acc = (float*)d_out;
    int n4      = n_total * EMB_DIM / 4;
    int user_n4 = n_users * EMB_DIM / 4;

    lgcn_init<<<(n4 + 255) / 256, 256, 0, stream>>>(user_w, item_w, acc, x,
                                                    btotal, nb, user_n4, n4);

    k_hist<<<nparts, HT, 0, stream>>>(erow, btotal, nb, nnz);
    k_scan_buckets<<<1, 256, 0, stream>>>(btotal, bbase, gcur, nb);
    k_scatter_staged<<<nparts, PT, 0, stream>>>(erow, ecol, eval_, gcur, ebuf, nb, nnz);

    // 3 propagation layers, ping-pong x/y, accumulate into d_out
    unsigned short* xin = x;
    unsigned short* yout = y;
    for (int layer = 0; layer < 3; ++layer) {
        const bool last = (layer == 2);
        lgcn_spmm_bucket<<<nb, 256, 0, stream>>>(
            bbase, btotal, ebuf, xin, yout, acc, 0.25f, last ? 1 : 0, n_total);
        unsigned short* t = xin; xin = yout; yout = t;
    }
}

// Round 3
// 651.537 us; speedup vs baseline: 6.7580x; 6.7580x over previous
//
#include <hip/hip_runtime.h>

#define EMB_DIM 64
#define BSHIFT 7
#define BROWS 128              // rows per bucket
#define NB_MAX 2048            // hist kernel (global-sized)
#define NB_SCAT 1216           // scatter LDS arrays; nb = 1172 for this problem
#define EPB 8192               // edges per partition block
#define PT 512                 // scatter-kernel threads
#define HT 256                 // hist-kernel threads

// bucket-stage pack: col (18b) | row_local (7b) << 18 ; val in high 32
static __device__ __forceinline__ unsigned long long pack_b(int rl, int c, float v) {
    unsigned int lo = (unsigned int)c | ((unsigned int)rl << 18);
    return (unsigned long long)lo | ((unsigned long long)__float_as_uint(v) << 32);
}
// final CSR pack: col | val<<32
static __device__ __forceinline__ unsigned long long pack_e(unsigned int c, unsigned int vbits) {
    return (unsigned long long)c | ((unsigned long long)vbits << 32);
}

static __device__ __forceinline__ unsigned short f2bf(float f) {   // RNE
    unsigned int u = __float_as_uint(f);
    return (unsigned short)((u + 0x7FFFu + ((u >> 16) & 1u)) >> 16);
}
static __device__ __forceinline__ float bf2f(unsigned short b) {
    return __uint_as_float((unsigned int)b << 16);
}

// ---------- init: acc(fp32) = concat(user,item); x(bf16) = same; zero btotal ----------
__global__ void lgcn_init(const float* __restrict__ user_w,
                          const float* __restrict__ item_w,
                          float* __restrict__ acc,
                          unsigned short* __restrict__ x,
                          int* __restrict__ btotal, int nb,
                          int user_n4, int n4) {
    int i = blockIdx.x * blockDim.x + threadIdx.x;
    if (i < nb) btotal[i] = 0;
    if (i >= n4) return;
    float4 v;
    if (i < user_n4) v = ((const float4*)user_w)[i];
    else             v = ((const float4*)item_w)[i - user_n4];
    ((float4*)acc)[i] = v;
    ushort4 b;
    b.x = f2bf(v.x); b.y = f2bf(v.y); b.z = f2bf(v.z); b.w = f2bf(v.w);
    ((ushort4*)x)[i] = b;
}

// ---------- pass 1: per-block LDS hist -> global bucket totals ----------
__global__ void k_hist(const int* __restrict__ erow, int* __restrict__ btotal,
                       int nb, long long nnz) {
    __shared__ int h[NB_MAX];
    int t = threadIdx.x;
    for (int b = t; b < nb; b += HT) h[b] = 0;
    __syncthreads();
    long long base = (long long)blockIdx.x * EPB;
    const int4* erow4 = (const int4*)erow;
    #pragma unroll
    for (int k = 0; k < EPB / HT / 4; ++k) {
        long long e = base + (long long)(k * HT + t) * 4;
        if (e + 4 <= nnz) {
            int4 r = erow4[e >> 2];
            atomicAdd(&h[r.x >> BSHIFT], 1);
            atomicAdd(&h[r.y >> BSHIFT], 1);
            atomicAdd(&h[r.z >> BSHIFT], 1);
            atomicAdd(&h[r.w >> BSHIFT], 1);
        } else if (e < nnz) {
            for (long long q = e; q < nnz; ++q) atomicAdd(&h[erow[q] >> BSHIFT], 1);
        }
    }
    __syncthreads();
    for (int b = t; b < nb; b += HT) {
        int c = h[b];
        if (c) atomicAdd(&btotal[b], c);
    }
}

// ---------- pass 2: exclusive scan over bucket totals -> bbase, gcur ----------
__global__ void k_scan_buckets(const int* __restrict__ btotal, int* __restrict__ bbase,
                               int* __restrict__ gcur, int nb) {
    __shared__ int s[256];
    int t = threadIdx.x;
    int v[8]; int tot = 0;
    #pragma unroll
    for (int k = 0; k < 8; ++k) {
        int idx = t * 8 + k;
        v[k] = (idx < nb) ? btotal[idx] : 0;
        tot += v[k];
    }
    s[t] = tot; __syncthreads();
    for (int d = 1; d < 256; d <<= 1) {
        int add = (t >= d) ? s[t - d] : 0;
        __syncthreads(); s[t] += add; __syncthreads();
    }
    int off = s[t] - tot;
    #pragma unroll
    for (int k = 0; k < 8; ++k) {
        int idx = t * 8 + k;
        if (idx < nb) { bbase[idx] = off; gcur[idx] = off; }
        off += v[k];
    }
}

// ---------- pass 3: LDS-staged bucket-sorted scatter, coalesced write-out ----------
__global__ __launch_bounds__(PT) void k_scatter_staged(
        const int* __restrict__ erow, const int* __restrict__ ecol,
        const float* __restrict__ eval_, int* __restrict__ gcur,
        unsigned long long* __restrict__ ebuf, int nb, long long nnz) {
    __shared__ unsigned long long staged[EPB];   // 64 KB
    __shared__ unsigned short sbid[EPB];         // 16 KB
    __shared__ int lhist[NB_SCAT];               // 4.75 KB (count -> delta)
    __shared__ int lscan[NB_SCAT];               // 4.75 KB
    __shared__ int lcur[NB_SCAT];                // 4.75 KB
    __shared__ int tsum[PT];                     // 2 KB

    int t = threadIdx.x;
    for (int b = t; b < nb; b += PT) lhist[b] = 0;
    __syncthreads();

    long long base = (long long)blockIdx.x * EPB;
    int m = (int)((nnz - base < (long long)EPB) ? (nnz - base) : (long long)EPB);

    // local histogram of this block's edges
    #pragma unroll
    for (int k = 0; k < EPB / PT / 4; ++k) {
        long long e = base + (long long)(k * PT + t) * 4;
        if (e + 4 <= nnz) {
            int4 r = ((const int4*)erow)[e >> 2];
            atomicAdd(&lhist[r.x >> BSHIFT], 1);
            atomicAdd(&lhist[r.y >> BSHIFT], 1);
            atomicAdd(&lhist[r.z >> BSHIFT], 1);
            atomicAdd(&lhist[r.w >> BSHIFT], 1);
        } else if (e < nnz) {
            for (long long q = e; q < nnz; ++q) atomicAdd(&lhist[erow[q] >> BSHIFT], 1);
        }
    }
    __syncthreads();

    // block exclusive scan over nb buckets
    int per = (nb + PT - 1) / PT;
    int first = t * per;
    int s = 0;
    for (int k = 0; k < per; ++k) {
        int b = first + k;
        if (b < nb) s += lhist[b];
    }
    tsum[t] = s;
    __syncthreads();
    for (int d = 1; d < PT; d <<= 1) {
        int add = (t >= d) ? tsum[t - d] : 0;
        __syncthreads(); tsum[t] += add; __syncthreads();
    }
    int off = tsum[t] - s;
    for (int k = 0; k < per; ++k) {
        int b = first + k;
        if (b < nb) { lscan[b] = off; lcur[b] = off; off += lhist[b]; }
    }
    __syncthreads();

    // reserve contiguous global chunks; lhist becomes delta = gbase - lstart
    for (int b = t; b < nb; b += PT) {
        int c = lhist[b];
        int g = c ? atomicAdd(&gcur[b], c) : 0;
        lhist[b] = g - lscan[b];
    }
    __syncthreads();

    // stage-in: bucket-sorted within LDS
    #pragma unroll
    for (int k = 0; k < EPB / PT / 4; ++k) {
        long long e = base + (long long)(k * PT + t) * 4;
        if (e + 4 <= nnz) {
            int4   r = ((const int4*)erow)[e >> 2];
            int4   c = ((const int4*)ecol)[e >> 2];
            float4 v = ((const float4*)eval_)[e >> 2];
            int b0 = r.x >> BSHIFT, b1 = r.y >> BSHIFT, b2 = r.z >> BSHIFT, b3 = r.w >> BSHIFT;
            int p0 = atomicAdd(&lcur[b0], 1);
            int p1 = atomicAdd(&lcur[b1], 1);
            int p2 = atomicAdd(&lcur[b2], 1);
            int p3 = atomicAdd(&lcur[b3], 1);
            staged[p0] = pack_b(r.x & (BROWS - 1), c.x, v.x); sbid[p0] = (unsigned short)b0;
            staged[p1] = pack_b(r.y & (BROWS - 1), c.y, v.y); sbid[p1] = (unsigned short)b1;
            staged[p2] = pack_b(r.z & (BROWS - 1), c.z, v.z); sbid[p2] = (unsigned short)b2;
            staged[p3] = pack_b(r.w & (BROWS - 1), c.w, v.w); sbid[p3] = (unsigned short)b3;
        } else if (e < nnz) {
            for (long long q = e; q < nnz; ++q) {
                int r = erow[q]; int b = r >> BSHIFT;
                int p = atomicAdd(&lcur[b], 1);
                staged[p] = pack_b(r & (BROWS - 1), ecol[q], eval_[q]);
                sbid[p] = (unsigned short)b;
            }
        }
    }
    __syncthreads();

    // write-out: consecutive staged entries -> contiguous destination runs
    for (int i = t; i < m; i += PT) {
        unsigned long long v = staged[i];
        int b = sbid[i];
        __builtin_nontemporal_store(v, &ebuf[lhist[b] + i]);
    }
}

// ---------- pass 4: per-bucket counting sort -> exact CSR (edges + row_ptr) ----------
__global__ void k_sort_bucket(const int* __restrict__ bbase, const int* __restrict__ btotal,
                              const unsigned long long* __restrict__ ebuf,
                              unsigned long long* __restrict__ edges,
                              int* __restrict__ row_ptr,
                              int nb, int n, long long nnz) {
    __shared__ int cnt[BROWS];
    __shared__ int sc[BROWS];
    __shared__ int cur[BROWS];
    int t = threadIdx.x;
    int bkt = blockIdx.x;
    if (t < BROWS) cnt[t] = 0;
    __syncthreads();
    int start = bbase[bkt];
    int m = btotal[bkt];
    for (int i = t; i < m; i += 256) {
        unsigned int lo = (unsigned int)ebuf[start + i];
        atomicAdd(&cnt[lo >> 18], 1);
    }
    __syncthreads();
    if (t < BROWS) sc[t] = cnt[t];
    __syncthreads();
    for (int d = 1; d < BROWS; d <<= 1) {
        int v = (t < BROWS && t >= d) ? sc[t - d] : 0;
        __syncthreads();
        if (t < BROWS) sc[t] += v;
        __syncthreads();
    }
    int r0 = bkt << BSHIFT;
    if (t < BROWS) {
        int excl = sc[t] - cnt[t];
        cur[t] = start + excl;
        if (r0 + t < n) row_ptr[r0 + t] = start + excl;
    }
    if (t == 0 && bkt == nb - 1) row_ptr[n] = (int)nnz;
    __syncthreads();
    for (int i = t; i < m; i += 256) {
        unsigned long long e = ebuf[start + i];
        unsigned int lo = (unsigned int)e;
        int p = atomicAdd(&cur[lo >> 18], 1);
        edges[p] = pack_e(lo & 0x3FFFFu, (unsigned int)(e >> 32));
    }
}

// ---------- CSR SpMM: one wave per row, lane = dim; bf16 gather, fp32 acc ----------
__global__ void lgcn_spmm_csr(const int* __restrict__ row_ptr,
                              const unsigned long long* __restrict__ edges,
                              const unsigned short* __restrict__ x,
                              unsigned short* __restrict__ y,
                              float* __restrict__ out,
                              float scale, int is_last, int n) {
    int w = (blockIdx.x * blockDim.x + threadIdx.x) >> 6;
    int lane = threadIdx.x & 63;
    if (w >= n) return;
    int start = row_ptr[w];
    int end   = row_ptr[w + 1];
    float acc = 0.f;
    int j = start;
    for (; j + 4 <= end; j += 4) {
        unsigned long long e0 = edges[j],     e1 = edges[j + 1];
        unsigned long long e2 = edges[j + 2], e3 = edges[j + 3];
        unsigned short u0 = x[(size_t)(unsigned int)e0 * EMB_DIM + lane];
        unsigned short u1 = x[(size_t)(unsigned int)e1 * EMB_DIM + lane];
        unsigned short u2 = x[(size_t)(unsigned int)e2 * EMB_DIM + lane];
        unsigned short u3 = x[(size_t)(unsigned int)e3 * EMB_DIM + lane];
        acc += __uint_as_float((unsigned int)(e0 >> 32)) * bf2f(u0)
             + __uint_as_float((unsigned int)(e1 >> 32)) * bf2f(u1)
             + __uint_as_float((unsigned int)(e2 >> 32)) * bf2f(u2)
             + __uint_as_float((unsigned int)(e3 >> 32)) * bf2f(u3);
    }
    for (; j < end; ++j) {
        unsigned long long e = edges[j];
        acc += __uint_as_float((unsigned int)(e >> 32))
             * bf2f(x[(size_t)(unsigned int)e * EMB_DIM + lane]);
    }
    size_t oi = (size_t)w * EMB_DIM + lane;
    y[oi] = f2bf(acc);
    float a = out[oi] + acc;
    out[oi] = is_last ? a * scale : a;
}

extern "C" void kernel_launch(void* const* d_in, const int* in_sizes, int n_in,
                              void* d_out, int out_size, void* d_ws, size_t ws_size,
                              hipStream_t stream) {
    const float* user_w = (const float*)d_in[0];
    const float* item_w = (const float*)d_in[1];
    const int*   erow   = (const int*)d_in[2];
    const int*   ecol   = (const int*)d_in[3];
    const float* eval_  = (const float*)d_in[4];

    int n_users = in_sizes[0] / EMB_DIM;
    int n_items = in_sizes[1] / EMB_DIM;
    int n_total = n_users + n_items;
    long long nnz = in_sizes[2];

    int nb     = (n_total + BROWS - 1) >> BSHIFT;
    int nparts = (int)((nnz + EPB - 1) / EPB);

    // workspace layout
    char* ws = (char*)d_ws;
    unsigned short* x = (unsigned short*)ws;    ws += (size_t)n_total * EMB_DIM * 2;
    unsigned short* y = (unsigned short*)ws;    ws += (size_t)n_total * EMB_DIM * 2;
    unsigned long long* ebuf  = (unsigned long long*)ws; ws += (size_t)nnz * 8;
    unsigned long long* edges = (unsigned long long*)ws; ws += (size_t)nnz * 8;
    int* btotal = (int*)ws;                     ws += (size_t)nb * 4;
    int* bbase  = (int*)ws;                     ws += (size_t)nb * 4;
    int* gcur   = (int*)ws;                     ws += (size_t)nb * 4;
    int* row_ptr= (int*)ws;                     ws += (size_t)(n_total + 1) * 4;

    float* acc = (float*)d_out;
    int n4      = n_total * EMB_DIM / 4;
    int user_n4 = n_users * EMB_DIM / 4;

    lgcn_init<<<(n4 + 255) / 256, 256, 0, stream>>>(user_w, item_w, acc, x,
                                                    btotal, nb, user_n4, n4);

    k_hist<<<nparts, HT, 0, stream>>>(erow, btotal, nb, nnz);
    k_scan_buckets<<<1, 256, 0, stream>>>(btotal, bbase, gcur, nb);
    k_scatter_staged<<<nparts, PT, 0, stream>>>(erow, ecol, eval_, gcur, ebuf, nb, nnz);
    k_sort_bucket<<<nb, 256, 0, stream>>>(bbase, btotal, ebuf, edges, row_ptr, nb, n_total, nnz);

    // 3 propagation layers, ping-pong x/y, accumulate into d_out
    unsigned short* xin = x;
    unsigned short* yout = y;
    for (int layer = 0; layer < 3; ++layer) {
        const bool last = (layer == 2);
        int blocks = (n_total * 64 + 255) / 256;
        lgcn_spmm_csr<<<blocks, 256, 0, stream>>>(
            row_ptr, edges, xin, yout, acc, 0.25f, last ? 1 : 0, n_total);
        unsigned short* t = xin; xin = yout; yout = t;
    }
}

// Round 4
// 599.269 us; speedup vs baseline: 7.3474x; 1.0872x over previous
//
#include <hip/hip_runtime.h>

#define EMB_DIM 64
#define BSHIFT 7
#define BROWS 128              // rows per bucket
#define NB_MAX 2048            // hist kernel (global-sized)
#define NB_SCAT 1216           // scatter LDS arrays; nb = 1172 for this problem
#define EPB 8192               // edges per partition block
#define PT 512                 // scatter-kernel threads
#define HT 256                 // hist-kernel threads

// bucket-stage pack: col (18b) | row_local (7b) << 18 ; val in high 32
static __device__ __forceinline__ unsigned long long pack_b(int rl, int c, float v) {
    unsigned int lo = (unsigned int)c | ((unsigned int)rl << 18);
    return (unsigned long long)lo | ((unsigned long long)__float_as_uint(v) << 32);
}
// final CSR pack: col | val<<32
static __device__ __forceinline__ unsigned long long pack_e(unsigned int c, unsigned int vbits) {
    return (unsigned long long)c | ((unsigned long long)vbits << 32);
}

static __device__ __forceinline__ unsigned short f2bf(float f) {   // RNE
    unsigned int u = __float_as_uint(f);
    return (unsigned short)((u + 0x7FFFu + ((u >> 16) & 1u)) >> 16);
}
static __device__ __forceinline__ float bf2f(unsigned short b) {
    return __uint_as_float((unsigned int)b << 16);
}

// ---------- init: acc(fp32) = concat(user,item); x(bf16) = same; zero btotal ----------
__global__ void lgcn_init(const float* __restrict__ user_w,
                          const float* __restrict__ item_w,
                          float* __restrict__ acc,
                          unsigned short* __restrict__ x,
                          int* __restrict__ btotal, int nb,
                          int user_n4, int n4) {
    int i = blockIdx.x * blockDim.x + threadIdx.x;
    if (i < nb) btotal[i] = 0;
    if (i >= n4) return;
    float4 v;
    if (i < user_n4) v = ((const float4*)user_w)[i];
    else             v = ((const float4*)item_w)[i - user_n4];
    ((float4*)acc)[i] = v;
    ushort4 b;
    b.x = f2bf(v.x); b.y = f2bf(v.y); b.z = f2bf(v.z); b.w = f2bf(v.w);
    ((ushort4*)x)[i] = b;
}

// ---------- pass 1: per-block LDS hist -> global bucket totals ----------
__global__ void k_hist(const int* __restrict__ erow, int* __restrict__ btotal,
                       int nb, long long nnz) {
    __shared__ int h[NB_MAX];
    int t = threadIdx.x;
    for (int b = t; b < nb; b += HT) h[b] = 0;
    __syncthreads();
    long long base = (long long)blockIdx.x * EPB;
    const int4* erow4 = (const int4*)erow;
    #pragma unroll
    for (int k = 0; k < EPB / HT / 4; ++k) {
        long long e = base + (long long)(k * HT + t) * 4;
        if (e + 4 <= nnz) {
            int4 r = erow4[e >> 2];
            atomicAdd(&h[r.x >> BSHIFT], 1);
            atomicAdd(&h[r.y >> BSHIFT], 1);
            atomicAdd(&h[r.z >> BSHIFT], 1);
            atomicAdd(&h[r.w >> BSHIFT], 1);
        } else if (e < nnz) {
            for (long long q = e; q < nnz; ++q) atomicAdd(&h[erow[q] >> BSHIFT], 1);
        }
    }
    __syncthreads();
    for (int b = t; b < nb; b += HT) {
        int c = h[b];
        if (c) atomicAdd(&btotal[b], c);
    }
}

// ---------- pass 2: exclusive scan over bucket totals -> bbase, gcur ----------
__global__ void k_scan_buckets(const int* __restrict__ btotal, int* __restrict__ bbase,
                               int* __restrict__ gcur, int nb) {
    __shared__ int s[256];
    int t = threadIdx.x;
    int v[8]; int tot = 0;
    #pragma unroll
    for (int k = 0; k < 8; ++k) {
        int idx = t * 8 + k;
        v[k] = (idx < nb) ? btotal[idx] : 0;
        tot += v[k];
    }
    s[t] = tot; __syncthreads();
    for (int d = 1; d < 256; d <<= 1) {
        int add = (t >= d) ? s[t - d] : 0;
        __syncthreads(); s[t] += add; __syncthreads();
    }
    int off = s[t] - tot;
    #pragma unroll
    for (int k = 0; k < 8; ++k) {
        int idx = t * 8 + k;
        if (idx < nb) { bbase[idx] = off; gcur[idx] = off; }
        off += v[k];
    }
}

// ---------- pass 3: LDS-staged bucket-sorted scatter, coalesced write-out ----------
__global__ __launch_bounds__(PT) void k_scatter_staged(
        const int* __restrict__ erow, const int* __restrict__ ecol,
        const float* __restrict__ eval_, int* __restrict__ gcur,
        unsigned long long* __restrict__ ebuf, int nb, long long nnz) {
    __shared__ unsigned long long staged[EPB];   // 64 KB
    __shared__ unsigned short sbid[EPB];         // 16 KB
    __shared__ int lhist[NB_SCAT];               // 4.75 KB (count -> delta)
    __shared__ int lscan[NB_SCAT];               // 4.75 KB
    __shared__ int lcur[NB_SCAT];                // 4.75 KB
    __shared__ int tsum[PT];                     // 2 KB

    int t = threadIdx.x;
    for (int b = t; b < nb; b += PT) lhist[b] = 0;
    __syncthreads();

    long long base = (long long)blockIdx.x * EPB;
    int m = (int)((nnz - base < (long long)EPB) ? (nnz - base) : (long long)EPB);

    // local histogram of this block's edges
    #pragma unroll
    for (int k = 0; k < EPB / PT / 4; ++k) {
        long long e = base + (long long)(k * PT + t) * 4;
        if (e + 4 <= nnz) {
            int4 r = ((const int4*)erow)[e >> 2];
            atomicAdd(&lhist[r.x >> BSHIFT], 1);
            atomicAdd(&lhist[r.y >> BSHIFT], 1);
            atomicAdd(&lhist[r.z >> BSHIFT], 1);
            atomicAdd(&lhist[r.w >> BSHIFT], 1);
        } else if (e < nnz) {
            for (long long q = e; q < nnz; ++q) atomicAdd(&lhist[erow[q] >> BSHIFT], 1);
        }
    }
    __syncthreads();

    // block exclusive scan over nb buckets
    int per = (nb + PT - 1) / PT;
    int first = t * per;
    int s = 0;
    for (int k = 0; k < per; ++k) {
        int b = first + k;
        if (b < nb) s += lhist[b];
    }
    tsum[t] = s;
    __syncthreads();
    for (int d = 1; d < PT; d <<= 1) {
        int add = (t >= d) ? tsum[t - d] : 0;
        __syncthreads(); tsum[t] += add; __syncthreads();
    }
    int off = tsum[t] - s;
    for (int k = 0; k < per; ++k) {
        int b = first + k;
        if (b < nb) { lscan[b] = off; lcur[b] = off; off += lhist[b]; }
    }
    __syncthreads();

    // reserve contiguous global chunks; lhist becomes delta = gbase - lstart
    for (int b = t; b < nb; b += PT) {
        int c = lhist[b];
        int g = c ? atomicAdd(&gcur[b], c) : 0;
        lhist[b] = g - lscan[b];
    }
    __syncthreads();

    // stage-in: bucket-sorted within LDS
    #pragma unroll
    for (int k = 0; k < EPB / PT / 4; ++k) {
        long long e = base + (long long)(k * PT + t) * 4;
        if (e + 4 <= nnz) {
            int4   r = ((const int4*)erow)[e >> 2];
            int4   c = ((const int4*)ecol)[e >> 2];
            float4 v = ((const float4*)eval_)[e >> 2];
            int b0 = r.x >> BSHIFT, b1 = r.y >> BSHIFT, b2 = r.z >> BSHIFT, b3 = r.w >> BSHIFT;
            int p0 = atomicAdd(&lcur[b0], 1);
            int p1 = atomicAdd(&lcur[b1], 1);
            int p2 = atomicAdd(&lcur[b2], 1);
            int p3 = atomicAdd(&lcur[b3], 1);
            staged[p0] = pack_b(r.x & (BROWS - 1), c.x, v.x); sbid[p0] = (unsigned short)b0;
            staged[p1] = pack_b(r.y & (BROWS - 1), c.y, v.y); sbid[p1] = (unsigned short)b1;
            staged[p2] = pack_b(r.z & (BROWS - 1), c.z, v.z); sbid[p2] = (unsigned short)b2;
            staged[p3] = pack_b(r.w & (BROWS - 1), c.w, v.w); sbid[p3] = (unsigned short)b3;
        } else if (e < nnz) {
            for (long long q = e; q < nnz; ++q) {
                int r = erow[q]; int b = r >> BSHIFT;
                int p = atomicAdd(&lcur[b], 1);
                staged[p] = pack_b(r & (BROWS - 1), ecol[q], eval_[q]);
                sbid[p] = (unsigned short)b;
            }
        }
    }
    __syncthreads();

    // write-out: consecutive staged entries -> contiguous destination runs
    for (int i = t; i < m; i += PT) {
        unsigned long long v = staged[i];
        int b = sbid[i];
        __builtin_nontemporal_store(v, &ebuf[lhist[b] + i]);
    }
}

// ---------- pass 4: per-bucket counting sort -> exact CSR (edges + row_ptr) ----------
__global__ void k_sort_bucket(const int* __restrict__ bbase, const int* __restrict__ btotal,
                              const unsigned long long* __restrict__ ebuf,
                              unsigned long long* __restrict__ edges,
                              int* __restrict__ row_ptr,
                              int nb, int n, long long nnz) {
    __shared__ int cnt[BROWS];
    __shared__ int sc[BROWS];
    __shared__ int cur[BROWS];
    int t = threadIdx.x;
    int bkt = blockIdx.x;
    if (t < BROWS) cnt[t] = 0;
    __syncthreads();
    int start = bbase[bkt];
    int m = btotal[bkt];
    for (int i = t; i < m; i += 256) {
        unsigned int lo = (unsigned int)ebuf[start + i];
        atomicAdd(&cnt[lo >> 18], 1);
    }
    __syncthreads();
    if (t < BROWS) sc[t] = cnt[t];
    __syncthreads();
    for (int d = 1; d < BROWS; d <<= 1) {
        int v = (t < BROWS && t >= d) ? sc[t - d] : 0;
        __syncthreads();
        if (t < BROWS) sc[t] += v;
        __syncthreads();
    }
    int r0 = bkt << BSHIFT;
    if (t < BROWS) {
        int excl = sc[t] - cnt[t];
        cur[t] = start + excl;
        if (r0 + t < n) row_ptr[r0 + t] = start + excl;
    }
    if (t == 0 && bkt == nb - 1) row_ptr[n] = (int)nnz;
    __syncthreads();
    for (int i = t; i < m; i += 256) {
        unsigned long long e = ebuf[start + i];
        unsigned int lo = (unsigned int)e;
        int p = atomicAdd(&cur[lo >> 18], 1);
        edges[p] = pack_e(lo & 0x3FFFFu, (unsigned int)(e >> 32));
    }
}

// ---------- CSR SpMM: one wave per row, lane = dim; 8-deep pipelined gathers ----------
__global__ void lgcn_spmm_csr(const int* __restrict__ row_ptr,
                              const unsigned long long* __restrict__ edges,
                              const unsigned short* __restrict__ x,
                              unsigned short* __restrict__ y,
                              float* __restrict__ out,
                              float scale, int is_last, int n) {
    int w = (blockIdx.x * blockDim.x + threadIdx.x) >> 6;
    int lane = threadIdx.x & 63;
    if (w >= n) return;
    int start = row_ptr[w];
    int end   = row_ptr[w + 1];
    int len   = end - start;
    float acc = 0.f;
    int nfull = len >> 3;
    int j = start;

    if (nfull) {
        unsigned long long e[8];
        #pragma unroll
        for (int k = 0; k < 8; ++k) e[k] = edges[j + k];
        // pipelined full blocks: gathers for block b overlap edge loads for b+1
        for (int b = 1; b < nfull; ++b) {
            unsigned short u[8];
            #pragma unroll
            for (int k = 0; k < 8; ++k)
                u[k] = x[(size_t)(unsigned int)e[k] * EMB_DIM + lane];
            unsigned long long e2[8];
            #pragma unroll
            for (int k = 0; k < 8; ++k) e2[k] = edges[j + 8 + k];
            float s = 0.f;
            #pragma unroll
            for (int k = 0; k < 8; ++k)
                s += __uint_as_float((unsigned int)(e[k] >> 32)) * bf2f(u[k]);
            acc += s;
            #pragma unroll
            for (int k = 0; k < 8; ++k) e[k] = e2[k];
            j += 8;
        }
        // drain last full block
        {
            unsigned short u[8];
            #pragma unroll
            for (int k = 0; k < 8; ++k)
                u[k] = x[(size_t)(unsigned int)e[k] * EMB_DIM + lane];
            float s = 0.f;
            #pragma unroll
            for (int k = 0; k < 8; ++k)
                s += __uint_as_float((unsigned int)(e[k] >> 32)) * bf2f(u[k]);
            acc += s;
            j += 8;
        }
    }
    // predicated tail: all tail gathers in flight at once (clamped index, zeroed val)
    int rem = end - j;
    if (rem) {
        unsigned long long e[8];
        #pragma unroll
        for (int k = 0; k < 8; ++k)
            e[k] = edges[(k < rem) ? (j + k) : (end - 1)];
        unsigned short u[8];
        #pragma unroll
        for (int k = 0; k < 8; ++k)
            u[k] = x[(size_t)(unsigned int)e[k] * EMB_DIM + lane];
        float s = 0.f;
        #pragma unroll
        for (int k = 0; k < 8; ++k) {
            float v = (k < rem) ? __uint_as_float((unsigned int)(e[k] >> 32)) : 0.f;
            s += v * bf2f(u[k]);
        }
        acc += s;
    }

    size_t oi = (size_t)w * EMB_DIM + lane;
    y[oi] = f2bf(acc);
    float a = out[oi] + acc;
    out[oi] = is_last ? a * scale : a;
}

extern "C" void kernel_launch(void* const* d_in, const int* in_sizes, int n_in,
                              void* d_out, int out_size, void* d_ws, size_t ws_size,
                              hipStream_t stream) {
    const float* user_w = (const float*)d_in[0];
    const float* item_w = (const float*)d_in[1];
    const int*   erow   = (const int*)d_in[2];
    const int*   ecol   = (const int*)d_in[3];
    const float* eval_  = (const float*)d_in[4];

    int n_users = in_sizes[0] / EMB_DIM;
    int n_items = in_sizes[1] / EMB_DIM;
    int n_total = n_users + n_items;
    long long nnz = in_sizes[2];

    int nb     = (n_total + BROWS - 1) >> BSHIFT;
    int nparts = (int)((nnz + EPB - 1) / EPB);

    // workspace layout
    char* ws = (char*)d_ws;
    unsigned short* x = (unsigned short*)ws;    ws += (size_t)n_total * EMB_DIM * 2;
    unsigned short* y = (unsigned short*)ws;    ws += (size_t)n_total * EMB_DIM * 2;
    unsigned long long* ebuf  = (unsigned long long*)ws; ws += (size_t)nnz * 8;
    unsigned long long* edges = (unsigned long long*)ws; ws += (size_t)nnz * 8;
    int* btotal = (int*)ws;                     ws += (size_t)nb * 4;
    int* bbase  = (int*)ws;                     ws += (size_t)nb * 4;
    int* gcur   = (int*)ws;                     ws += (size_t)nb * 4;
    int* row_ptr= (int*)ws;                     ws += (size_t)(n_total + 1) * 4;

    float* acc = (float*)d_out;
    int n4      = n_total * EMB_DIM / 4;
    int user_n4 = n_users * EMB_DIM / 4;

    lgcn_init<<<(n4 + 255) / 256, 256, 0, stream>>>(user_w, item_w, acc, x,
                                                    btotal, nb, user_n4, n4);

    k_hist<<<nparts, HT, 0, stream>>>(erow, btotal, nb, nnz);
    k_scan_buckets<<<1, 256, 0, stream>>>(btotal, bbase, gcur, nb);
    k_scatter_staged<<<nparts, PT, 0, stream>>>(erow, ecol, eval_, gcur, ebuf, nb, nnz);
    k_sort_bucket<<<nb, 256, 0, stream>>>(bbase, btotal, ebuf, edges, row_ptr, nb, n_total, nnz);

    // 3 propagation layers, ping-pong x/y, accumulate into d_out
    unsigned short* xin = x;
    unsigned short* yout = y;
    for (int layer = 0; layer < 3; ++layer) {
        const bool last = (layer == 2);
        int blocks = (n_total * 64 + 255) / 256;
        lgcn_spmm_csr<<<blocks, 256, 0, stream>>>(
            row_ptr, edges, xin, yout, acc, 0.25f, last ? 1 : 0, n_total);
        unsigned short* t = xin; xin = yout; yout = t;
    }
}

// Round 5
// 484.848 us; speedup vs baseline: 9.0814x; 1.2360x over previous
//
#include <hip/hip_runtime.h>

#define EMB_DIM 64
#define BSHIFT 7
#define BROWS 128              // rows per bucket
#define NB_MAX 2048            // hist kernel (global-sized)
#define NB_SCAT 1216           // scatter LDS arrays; nb = 1172 for this problem
#define EPB 8192               // edges per partition block
#define PT 512                 // scatter-kernel threads
#define HT 256                 // hist-kernel threads

// bucket-stage pack: col (18b) | row_local (7b) << 18 ; val in high 32
static __device__ __forceinline__ unsigned long long pack_b(int rl, int c, float v) {
    unsigned int lo = (unsigned int)c | ((unsigned int)rl << 18);
    return (unsigned long long)lo | ((unsigned long long)__float_as_uint(v) << 32);
}
// final CSR pack: col | val<<32
static __device__ __forceinline__ unsigned long long pack_e(unsigned int c, unsigned int vbits) {
    return (unsigned long long)c | ((unsigned long long)vbits << 32);
}

static __device__ __forceinline__ unsigned short f2bf(float f) {   // RNE
    unsigned int u = __float_as_uint(f);
    return (unsigned short)((u + 0x7FFFu + ((u >> 16) & 1u)) >> 16);
}
static __device__ __forceinline__ float bf2f(unsigned short b) {
    return __uint_as_float((unsigned int)b << 16);
}

// ---------- init: acc(fp32) = concat(user,item); x(bf16) = same; zero btotal ----------
__global__ void lgcn_init(const float* __restrict__ user_w,
                          const float* __restrict__ item_w,
                          float* __restrict__ acc,
                          unsigned short* __restrict__ x,
                          int* __restrict__ btotal, int nb,
                          int user_n4, int n4) {
    int i = blockIdx.x * blockDim.x + threadIdx.x;
    if (i < nb) btotal[i] = 0;
    if (i >= n4) return;
    float4 v;
    if (i < user_n4) v = ((const float4*)user_w)[i];
    else             v = ((const float4*)item_w)[i - user_n4];
    ((float4*)acc)[i] = v;
    ushort4 b;
    b.x = f2bf(v.x); b.y = f2bf(v.y); b.z = f2bf(v.z); b.w = f2bf(v.w);
    ((ushort4*)x)[i] = b;
}

// ---------- pass 1: per-block LDS hist -> global bucket totals ----------
__global__ void k_hist(const int* __restrict__ erow, int* __restrict__ btotal,
                       int nb, long long nnz) {
    __shared__ int h[NB_MAX];
    int t = threadIdx.x;
    for (int b = t; b < nb; b += HT) h[b] = 0;
    __syncthreads();
    long long base = (long long)blockIdx.x * EPB;
    const int4* erow4 = (const int4*)erow;
    #pragma unroll
    for (int k = 0; k < EPB / HT / 4; ++k) {
        long long e = base + (long long)(k * HT + t) * 4;
        if (e + 4 <= nnz) {
            int4 r = erow4[e >> 2];
            atomicAdd(&h[r.x >> BSHIFT], 1);
            atomicAdd(&h[r.y >> BSHIFT], 1);
            atomicAdd(&h[r.z >> BSHIFT], 1);
            atomicAdd(&h[r.w >> BSHIFT], 1);
        } else if (e < nnz) {
            for (long long q = e; q < nnz; ++q) atomicAdd(&h[erow[q] >> BSHIFT], 1);
        }
    }
    __syncthreads();
    for (int b = t; b < nb; b += HT) {
        int c = h[b];
        if (c) atomicAdd(&btotal[b], c);
    }
}

// ---------- pass 2: exclusive scan over bucket totals -> bbase, gcur ----------
__global__ void k_scan_buckets(const int* __restrict__ btotal, int* __restrict__ bbase,
                               int* __restrict__ gcur, int nb) {
    __shared__ int s[256];
    int t = threadIdx.x;
    int v[8]; int tot = 0;
    #pragma unroll
    for (int k = 0; k < 8; ++k) {
        int idx = t * 8 + k;
        v[k] = (idx < nb) ? btotal[idx] : 0;
        tot += v[k];
    }
    s[t] = tot; __syncthreads();
    for (int d = 1; d < 256; d <<= 1) {
        int add = (t >= d) ? s[t - d] : 0;
        __syncthreads(); s[t] += add; __syncthreads();
    }
    int off = s[t] - tot;
    #pragma unroll
    for (int k = 0; k < 8; ++k) {
        int idx = t * 8 + k;
        if (idx < nb) { bbase[idx] = off; gcur[idx] = off; }
        off += v[k];
    }
}

// ---------- pass 3: LDS-staged bucket-sorted scatter, coalesced write-out ----------
__global__ __launch_bounds__(PT) void k_scatter_staged(
        const int* __restrict__ erow, const int* __restrict__ ecol,
        const float* __restrict__ eval_, int* __restrict__ gcur,
        unsigned long long* __restrict__ ebuf, int nb, long long nnz) {
    __shared__ unsigned long long staged[EPB];   // 64 KB
    __shared__ unsigned short sbid[EPB];         // 16 KB
    __shared__ int lhist[NB_SCAT];               // 4.75 KB (count -> delta)
    __shared__ int lscan[NB_SCAT];               // 4.75 KB
    __shared__ int lcur[NB_SCAT];                // 4.75 KB
    __shared__ int tsum[PT];                     // 2 KB

    int t = threadIdx.x;
    for (int b = t; b < nb; b += PT) lhist[b] = 0;
    __syncthreads();

    long long base = (long long)blockIdx.x * EPB;
    int m = (int)((nnz - base < (long long)EPB) ? (nnz - base) : (long long)EPB);

    // local histogram of this block's edges
    #pragma unroll
    for (int k = 0; k < EPB / PT / 4; ++k) {
        long long e = base + (long long)(k * PT + t) * 4;
        if (e + 4 <= nnz) {
            int4 r = ((const int4*)erow)[e >> 2];
            atomicAdd(&lhist[r.x >> BSHIFT], 1);
            atomicAdd(&lhist[r.y >> BSHIFT], 1);
            atomicAdd(&lhist[r.z >> BSHIFT], 1);
            atomicAdd(&lhist[r.w >> BSHIFT], 1);
        } else if (e < nnz) {
            for (long long q = e; q < nnz; ++q) atomicAdd(&lhist[erow[q] >> BSHIFT], 1);
        }
    }
    __syncthreads();

    // block exclusive scan over nb buckets
    int per = (nb + PT - 1) / PT;
    int first = t * per;
    int s = 0;
    for (int k = 0; k < per; ++k) {
        int b = first + k;
        if (b < nb) s += lhist[b];
    }
    tsum[t] = s;
    __syncthreads();
    for (int d = 1; d < PT; d <<= 1) {
        int add = (t >= d) ? tsum[t - d] : 0;
        __syncthreads(); tsum[t] += add; __syncthreads();
    }
    int off = tsum[t] - s;
    for (int k = 0; k < per; ++k) {
        int b = first + k;
        if (b < nb) { lscan[b] = off; lcur[b] = off; off += lhist[b]; }
    }
    __syncthreads();

    // reserve contiguous global chunks; lhist becomes delta = gbase - lstart
    for (int b = t; b < nb; b += PT) {
        int c = lhist[b];
        int g = c ? atomicAdd(&gcur[b], c) : 0;
        lhist[b] = g - lscan[b];
    }
    __syncthreads();

    // stage-in: bucket-sorted within LDS
    #pragma unroll
    for (int k = 0; k < EPB / PT / 4; ++k) {
        long long e = base + (long long)(k * PT + t) * 4;
        if (e + 4 <= nnz) {
            int4   r = ((const int4*)erow)[e >> 2];
            int4   c = ((const int4*)ecol)[e >> 2];
            float4 v = ((const float4*)eval_)[e >> 2];
            int b0 = r.x >> BSHIFT, b1 = r.y >> BSHIFT, b2 = r.z >> BSHIFT, b3 = r.w >> BSHIFT;
            int p0 = atomicAdd(&lcur[b0], 1);
            int p1 = atomicAdd(&lcur[b1], 1);
            int p2 = atomicAdd(&lcur[b2], 1);
            int p3 = atomicAdd(&lcur[b3], 1);
            staged[p0] = pack_b(r.x & (BROWS - 1), c.x, v.x); sbid[p0] = (unsigned short)b0;
            staged[p1] = pack_b(r.y & (BROWS - 1), c.y, v.y); sbid[p1] = (unsigned short)b1;
            staged[p2] = pack_b(r.z & (BROWS - 1), c.z, v.z); sbid[p2] = (unsigned short)b2;
            staged[p3] = pack_b(r.w & (BROWS - 1), c.w, v.w); sbid[p3] = (unsigned short)b3;
        } else if (e < nnz) {
            for (long long q = e; q < nnz; ++q) {
                int r = erow[q]; int b = r >> BSHIFT;
                int p = atomicAdd(&lcur[b], 1);
                staged[p] = pack_b(r & (BROWS - 1), ecol[q], eval_[q]);
                sbid[p] = (unsigned short)b;
            }
        }
    }
    __syncthreads();

    // write-out: consecutive staged entries -> contiguous destination runs
    for (int i = t; i < m; i += PT) {
        unsigned long long v = staged[i];
        int b = sbid[i];
        __builtin_nontemporal_store(v, &ebuf[lhist[b] + i]);
    }
}

// ---------- pass 4: per-bucket counting sort -> exact CSR (edges + row_ptr) ----------
__global__ void k_sort_bucket(const int* __restrict__ bbase, const int* __restrict__ btotal,
                              const unsigned long long* __restrict__ ebuf,
                              unsigned long long* __restrict__ edges,
                              int* __restrict__ row_ptr,
                              int nb, int n, long long nnz) {
    __shared__ int cnt[BROWS];
    __shared__ int sc[BROWS];
    __shared__ int cur[BROWS];
    int t = threadIdx.x;
    int bkt = blockIdx.x;
    if (t < BROWS) cnt[t] = 0;
    __syncthreads();
    int start = bbase[bkt];
    int m = btotal[bkt];
    for (int i = t; i < m; i += 256) {
        unsigned int lo = (unsigned int)ebuf[start + i];
        atomicAdd(&cnt[lo >> 18], 1);
    }
    __syncthreads();
    if (t < BROWS) sc[t] = cnt[t];
    __syncthreads();
    for (int d = 1; d < BROWS; d <<= 1) {
        int v = (t < BROWS && t >= d) ? sc[t - d] : 0;
        __syncthreads();
        if (t < BROWS) sc[t] += v;
        __syncthreads();
    }
    int r0 = bkt << BSHIFT;
    if (t < BROWS) {
        int excl = sc[t] - cnt[t];
        cur[t] = start + excl;
        if (r0 + t < n) row_ptr[r0 + t] = start + excl;
    }
    if (t == 0 && bkt == nb - 1) row_ptr[n] = (int)nnz;
    __syncthreads();
    for (int i = t; i < m; i += 256) {
        unsigned long long e = ebuf[start + i];
        unsigned int lo = (unsigned int)e;
        int p = atomicAdd(&cur[lo >> 18], 1);
        edges[p] = pack_e(lo & 0x3FFFFu, (unsigned int)(e >> 32));
    }
}

// ---------- CSR SpMM: wave/row, scalar(SGPR) edge loads, pipelined gathers ----------
__global__ void lgcn_spmm_csr(const int* __restrict__ row_ptr,
                              const unsigned long long* __restrict__ edges,
                              const unsigned short* __restrict__ x,
                              unsigned short* __restrict__ y,
                              float* __restrict__ out,
                              float scale, int is_last, int n) {
    int w = (blockIdx.x * blockDim.x + threadIdx.x) >> 6;
    int lane = threadIdx.x & 63;
    if (w >= n) return;
    // force wave-uniformity into SGPRs: row_ptr and edges loads become s_load,
    // gather address becomes saddr(col<<7) + voffset(lane*2)
    w = __builtin_amdgcn_readfirstlane(w);
    int start = __builtin_amdgcn_readfirstlane(row_ptr[w]);
    int end   = __builtin_amdgcn_readfirstlane(row_ptr[w + 1]);
    int len   = end - start;
    float acc = 0.f;
    int nfull = len >> 3;
    int j = start;

    if (nfull) {
        unsigned long long e[8];
        #pragma unroll
        for (int k = 0; k < 8; ++k) e[k] = edges[j + k];
        // pipelined full blocks: gathers for block b overlap edge loads for b+1
        for (int b = 1; b < nfull; ++b) {
            unsigned short u[8];
            #pragma unroll
            for (int k = 0; k < 8; ++k)
                u[k] = x[(size_t)(unsigned int)e[k] * EMB_DIM + lane];
            unsigned long long e2[8];
            #pragma unroll
            for (int k = 0; k < 8; ++k) e2[k] = edges[j + 8 + k];
            float s = 0.f;
            #pragma unroll
            for (int k = 0; k < 8; ++k)
                s += __uint_as_float((unsigned int)(e[k] >> 32)) * bf2f(u[k]);
            acc += s;
            #pragma unroll
            for (int k = 0; k < 8; ++k) e[k] = e2[k];
            j += 8;
        }
        // drain last full block
        {
            unsigned short u[8];
            #pragma unroll
            for (int k = 0; k < 8; ++k)
                u[k] = x[(size_t)(unsigned int)e[k] * EMB_DIM + lane];
            float s = 0.f;
            #pragma unroll
            for (int k = 0; k < 8; ++k)
                s += __uint_as_float((unsigned int)(e[k] >> 32)) * bf2f(u[k]);
            acc += s;
            j += 8;
        }
    }
    // predicated tail: all tail gathers in flight at once (clamped index, zeroed val)
    int rem = end - j;
    if (rem) {
        unsigned long long e[8];
        #pragma unroll
        for (int k = 0; k < 8; ++k)
            e[k] = edges[(k < rem) ? (j + k) : (end - 1)];
        unsigned short u[8];
        #pragma unroll
        for (int k = 0; k < 8; ++k)
            u[k] = x[(size_t)(unsigned int)e[k] * EMB_DIM + lane];
        float s = 0.f;
        #pragma unroll
        for (int k = 0; k < 8; ++k) {
            float v = (k < rem) ? __uint_as_float((unsigned int)(e[k] >> 32)) : 0.f;
            s += v * bf2f(u[k]);
        }
        acc += s;
    }

    size_t oi = (size_t)w * EMB_DIM + lane;
    y[oi] = f2bf(acc);
    float a = out[oi] + acc;
    out[oi] = is_last ? a * scale : a;
}

extern "C" void kernel_launch(void* const* d_in, const int* in_sizes, int n_in,
                              void* d_out, int out_size, void* d_ws, size_t ws_size,
                              hipStream_t stream) {
    const float* user_w = (const float*)d_in[0];
    const float* item_w = (const float*)d_in[1];
    const int*   erow   = (const int*)d_in[2];
    const int*   ecol   = (const int*)d_in[3];
    const float* eval_  = (const float*)d_in[4];

    int n_users = in_sizes[0] / EMB_DIM;
    int n_items = in_sizes[1] / EMB_DIM;
    int n_total = n_users + n_items;
    long long nnz = in_sizes[2];

    int nb     = (n_total + BROWS - 1) >> BSHIFT;
    int nparts = (int)((nnz + EPB - 1) / EPB);

    // workspace layout
    char* ws = (char*)d_ws;
    unsigned short* x = (unsigned short*)ws;    ws += (size_t)n_total * EMB_DIM * 2;
    unsigned short* y = (unsigned short*)ws;    ws += (size_t)n_total * EMB_DIM * 2;
    unsigned long long* ebuf  = (unsigned long long*)ws; ws += (size_t)nnz * 8;
    unsigned long long* edges = (unsigned long long*)ws; ws += (size_t)nnz * 8;
    int* btotal = (int*)ws;                     ws += (size_t)nb * 4;
    int* bbase  = (int*)ws;                     ws += (size_t)nb * 4;
    int* gcur   = (int*)ws;                     ws += (size_t)nb * 4;
    int* row_ptr= (int*)ws;                     ws += (size_t)(n_total + 1) * 4;

    float* acc = (float*)d_out;
    int n4      = n_total * EMB_DIM / 4;
    int user_n4 = n_users * EMB_DIM / 4;

    lgcn_init<<<(n4 + 255) / 256, 256, 0, stream>>>(user_w, item_w, acc, x,
                                                    btotal, nb, user_n4, n4);

    k_hist<<<nparts, HT, 0, stream>>>(erow, btotal, nb, nnz);
    k_scan_buckets<<<1, 256, 0, stream>>>(btotal, bbase, gcur, nb);
    k_scatter_staged<<<nparts, PT, 0, stream>>>(erow, ecol, eval_, gcur, ebuf, nb, nnz);
    k_sort_bucket<<<nb, 256, 0, stream>>>(bbase, btotal, ebuf, edges, row_ptr, nb, n_total, nnz);

    // 3 propagation layers, ping-pong x/y, accumulate into d_out
    unsigned short* xin = x;
    unsigned short* yout = y;
    for (int layer = 0; layer < 3; ++layer) {
        const bool last = (layer == 2);
        int blocks = (n_total * 64 + 255) / 256;
        lgcn_spmm_csr<<<blocks, 256, 0, stream>>>(
            row_ptr, edges, xin, yout, acc, 0.25f, last ? 1 : 0, n_total);
        unsigned short* t = xin; xin = yout; yout = t;
    }
}